// Round 17
// baseline (478.434 us; speedup 1.0000x reference)
//
#include <hip/hip_runtime.h>
#include <math.h>

#define NN 100000
#define DD 128
#define CC 64
#define TT 8
#define NS 50000
#define G8 8
#define RPB 192             // rows per block-iteration: 12 waves x 16
#define MAXS 261            // A strips/g: ceil(50000/192)
#define MAXS_B 131          // B strips/g: ceil(25000/192)
#define T1MAX (G8 * MAXS)   // 2088
#define T2MAX (G8 * MAXS_B) // 1048
#define L2CAP 25000
#define ZINT4 200032        // (NN*8 + 128) ints / 4

typedef __attribute__((ext_vector_type(4))) float f32x4;
typedef __attribute__((ext_vector_type(8))) short bf16x8;
typedef unsigned short ushort_t;

__device__ __forceinline__ short f2bf(float f) {
    union { float f; unsigned u; } v; v.f = f;
    unsigned r = v.u + 0x7fffu + ((v.u >> 16) & 1u);
    return (short)(r >> 16);
}
__device__ __forceinline__ unsigned pk_bf16(float lo, float hi) {
    unsigned r;
    asm("v_cvt_pk_bf16_f32 %0, %1, %2" : "=v"(r) : "v"(lo), "v"(hi));
    return r;
}
// tanh-form GELU via hardware exp: max |diff| vs exact erf-GELU ~3e-3
__device__ __forceinline__ float gelu(float x) {
    float t = x + 0.044715f * x * x * x;
    return x / (1.0f + __expf(-1.5957691216f * t));
}

// ------- weights -> MFMA-fragment tables + zero pernode/cnts (one kernel) ----
__global__ void prep_all(const float* __restrict__ Wd1, const float* __restrict__ Wd2,
                         const float* __restrict__ Wu1, const float* __restrict__ Wu2,
                         short* __restrict__ pW1, short* __restrict__ pW2,
                         short* __restrict__ pW3, short* __restrict__ pW4,
                         int4* __restrict__ zbase) {
    int b = blockIdx.x;
    if (b >= 36) {
        int i = (b - 36) * 256 + threadIdx.x;
        if (i < ZINT4) zbase[i] = (int4){0, 0, 0, 0};
        return;
    }
    const float* W; short* dst; int KSTEPS, total, N, s0;
    if (b < 16)      { W = Wd1; dst = pW1; KSTEPS = 4; total = 4096; N = 256; s0 = b * 256; }
    else if (b < 24) { W = Wd2; dst = pW2; KSTEPS = 8; total = 2048; N = 64;  s0 = (b - 16) * 256; }
    else if (b < 28) { W = Wu1; dst = pW3; KSTEPS = 2; total = 1024; N = 128; s0 = (b - 24) * 256; }
    else             { W = Wu2; dst = pW4; KSTEPS = 4; total = 2048; N = 128; s0 = (b - 28) * 256; }
    int s = s0 + threadIdx.x;
    if (s >= total) return;
    int lane = s & 63;
    int ks = (s >> 6) % KSTEPS;
    int n = s / (64 * KSTEPS);
    int kb = ks * 32 + (lane >> 4) * 8;
    int col = n * 16 + (lane & 15);
    bf16x8 o;
    #pragma unroll
    for (int j = 0; j < 8; ++j) o[j] = f2bf(W[(size_t)(kb + j) * N + col]);
    *(bf16x8*)(dst + (size_t)s * 8) = o;
}

// -------- count + record contributor positions (packed u16 buckets) --------
__global__ void flagfill_kernel(const int* __restrict__ idx, int* __restrict__ pernode,
                                ushort_t* __restrict__ bucket) {
    int i = blockIdx.x * 256 + threadIdx.x;
    if (i >= G8 * NS) return;
    int g = i / NS, s = i - g * NS;
    int node = idx[i];
    int p = atomicAdd(&pernode[node * 8 + g], 1);
    if (p < 16) bucket[((size_t)node * 8 + g) * 16 + p] = (ushort_t)s;
}

// ------ list1: {pos,node} pairs with c==1; list2: nodes with c>=2 ----------
__global__ void compact2_kernel(const int* __restrict__ idx, const int* __restrict__ pernode,
                                int2* __restrict__ list1, int* __restrict__ cnts1,
                                int* __restrict__ list2, int* __restrict__ cnts2) {
    int g = blockIdx.y;
    int i = blockIdx.x * 256 + threadIdx.x;
    int lane = threadIdx.x & 63;
    bool a1 = false;
    int nd1 = 0;
    if (i < NS) {
        nd1 = idx[(size_t)g * NS + i];
        a1 = (pernode[nd1 * 8 + g] == 1);
    }
    unsigned long long m1 = __ballot(a1);
    int r1 = __popcll(m1 & ((1ull << lane) - 1ull));
    int c1 = __popcll(m1);
    int b1 = 0;
    if (lane == 0 && c1 > 0) b1 = atomicAdd(&cnts1[g], c1);
    b1 = __shfl(b1, 0);
    if (a1) list1[(size_t)g * NS + b1 + r1] = (int2){i, nd1};
    bool a2 = (i < NN) && (pernode[i * 8 + g] >= 2);
    unsigned long long m2 = __ballot(a2);
    int r2 = __popcll(m2 & ((1ull << lane) - 1ull));
    int c2 = __popcll(m2);
    int b2 = 0;
    if (lane == 0 && c2 > 0) b2 = atomicAdd(&cnts2[g], c2);
    b2 = __shfl(b2, 0);
    if (a2) list2[(size_t)g * L2CAP + b2 + r2] = i;
}

// ---- LN_d in A-fragment layout: v[32] -> afr[4]
__device__ __forceinline__ void ln_d_pack(
    const float (&v)[32], int kgrp,
    const float* __restrict__ lndg, const float* __restrict__ lndb, bf16x8 (&afr)[4]) {
    float s1 = 0.f;
    #pragma unroll
    for (int j = 0; j < 32; ++j) s1 += v[j];
    s1 += __shfl_xor(s1, 16); s1 += __shfl_xor(s1, 32);
    float mu = s1 * 0.0078125f;
    float s2 = 0.f;
    #pragma unroll
    for (int j = 0; j < 32; ++j) { float d = v[j] - mu; s2 += d * d; }
    s2 += __shfl_xor(s2, 16); s2 += __shfl_xor(s2, 32);
    float rs = rsqrtf(s2 * 0.0078125f + 1e-5f);
    union U8 { bf16x8 v8; unsigned u[4]; };
    const float* gp = lndg + kgrp * 8;
    const float* bbp = lndb + kgrp * 8;
    #pragma unroll
    for (int ks = 0; ks < 4; ++ks) {
        float4 g0 = *(const float4*)(gp + ks * 32);
        float4 g1 = *(const float4*)(gp + ks * 32 + 4);
        float4 c0 = *(const float4*)(bbp + ks * 32);
        float4 c1 = *(const float4*)(bbp + ks * 32 + 4);
        U8 t;
        t.u[0] = pk_bf16((v[ks*8+0]-mu)*rs*g0.x + c0.x, (v[ks*8+1]-mu)*rs*g0.y + c0.y);
        t.u[1] = pk_bf16((v[ks*8+2]-mu)*rs*g0.z + c0.z, (v[ks*8+3]-mu)*rs*g0.w + c0.w);
        t.u[2] = pk_bf16((v[ks*8+4]-mu)*rs*g1.x + c1.x, (v[ks*8+5]-mu)*rs*g1.y + c1.y);
        t.u[3] = pk_bf16((v[ks*8+6]-mu)*rs*g1.z + c1.z, (v[ks*8+7]-mu)*rs*g1.w + c1.w);
        afr[ks] = t.v8;
    }
}

// ---- MLP core (r13 version: 2KB wave buffer, ks2-chunked G1->G2)
__device__ __forceinline__ void mlp_core(
    const bf16x8 (&afr)[4], short* myb, int arow, int kgrp,
    const short* sW1, const short* sW2, const short* __restrict__ pW3, const short* sW4,
    const float* __restrict__ bd1, const float* __restrict__ bd2,
    const float* __restrict__ lnug, const float* __restrict__ lnub,
    const float* __restrict__ bu1, f32x4 (&acc4)[8]) {
    const int lane = kgrp * 16 + arow;
    f32x4 acc2[4];
    #pragma unroll
    for (int n = 0; n < 4; ++n) acc2[n] = (f32x4){0.f, 0.f, 0.f, 0.f};
    for (int ks2 = 0; ks2 < 8; ++ks2) {
        f32x4 a1v[2];
        a1v[0] = (f32x4){0.f, 0.f, 0.f, 0.f};
        a1v[1] = (f32x4){0.f, 0.f, 0.f, 0.f};
        #pragma unroll
        for (int ks1 = 0; ks1 < 4; ++ks1) {
            #pragma unroll
            for (int p = 0; p < 2; ++p) {
                bf16x8 bf = *(const bf16x8*)(sW1 + (size_t)((((2 * ks2 + p) << 2) | ks1) * 64 + lane) * 8);
                a1v[p] = __builtin_amdgcn_mfma_f32_16x16x32_bf16(afr[ks1], bf, a1v[p], 0, 0, 0);
            }
        }
        #pragma unroll
        for (int p = 0; p < 2; ++p) {
            float bias = bd1[(2 * ks2 + p) * 16 + arow];
            #pragma unroll
            for (int rr = 0; rr < 4; ++rr) {
                float vv = gelu(a1v[p][rr] + bias);
                int row = kgrp * 4 + rr;
                int byte = row * 64 + (((p * 16 + arow) * 2) ^ ((row & 3) << 4));
                myb[byte >> 1] = f2bf(vv);
            }
        }
        bf16x8 af2 = *(const bf16x8*)(myb + ((arow * 64 + ((kgrp * 16) ^ ((arow & 3) << 4))) >> 1));
        #pragma unroll
        for (int n2 = 0; n2 < 4; ++n2) {
            bf16x8 bf = *(const bf16x8*)(sW2 + (size_t)(((n2 << 3) | ks2) * 64 + lane) * 8);
            acc2[n2] = __builtin_amdgcn_mfma_f32_16x16x32_bf16(af2, bf, acc2[n2], 0, 0, 0);
        }
    }
    float hv[4][4];
    #pragma unroll
    for (int n2 = 0; n2 < 4; ++n2)
        #pragma unroll
        for (int rr = 0; rr < 4; ++rr)
            hv[n2][rr] = acc2[n2][rr] + bd2[n2 * 16 + arow];
    #pragma unroll
    for (int rr = 0; rr < 4; ++rr) {
        float sr = hv[0][rr] + hv[1][rr] + hv[2][rr] + hv[3][rr];
        sr += __shfl_xor(sr, 1); sr += __shfl_xor(sr, 2);
        sr += __shfl_xor(sr, 4); sr += __shfl_xor(sr, 8);
        float mu_u = sr * 0.015625f;
        float sq = 0.f;
        #pragma unroll
        for (int n2 = 0; n2 < 4; ++n2) { float d = hv[n2][rr] - mu_u; sq += d * d; }
        sq += __shfl_xor(sq, 1); sq += __shfl_xor(sq, 2);
        sq += __shfl_xor(sq, 4); sq += __shfl_xor(sq, 8);
        float rs_u = rsqrtf(sq * 0.015625f + 1e-5f);
        #pragma unroll
        for (int n2 = 0; n2 < 4; ++n2) {
            int cidx = n2 * 16 + arow;
            float nv = (hv[n2][rr] - mu_u) * rs_u * lnug[cidx] + lnub[cidx];
            int row = kgrp * 4 + rr;
            int byte = row * 128 + ((cidx * 2) ^ ((row & 7) << 4));
            myb[byte >> 1] = f2bf(nv);
        }
    }
    bf16x8 af3[2];
    #pragma unroll
    for (int ks3 = 0; ks3 < 2; ++ks3)
        af3[ks3] = *(const bf16x8*)(myb + ((arow * 128 + ((ks3 * 64 + kgrp * 16) ^ ((arow & 7) << 4))) >> 1));
    #pragma unroll
    for (int n = 0; n < 8; ++n) acc4[n] = (f32x4){0.f, 0.f, 0.f, 0.f};
    #pragma unroll
    for (int half = 0; half < 2; ++half) {
        f32x4 a3[4];
        #pragma unroll
        for (int n = 0; n < 4; ++n) a3[n] = (f32x4){0.f, 0.f, 0.f, 0.f};
        #pragma unroll
        for (int ks3 = 0; ks3 < 2; ++ks3) {
            #pragma unroll
            for (int n3h = 0; n3h < 4; ++n3h) {
                int n3 = half * 4 + n3h;
                bf16x8 bf = *(const bf16x8*)(pW3 + (size_t)(((n3 << 1) | ks3) * 64 + lane) * 8);
                a3[n3h] = __builtin_amdgcn_mfma_f32_16x16x32_bf16(af3[ks3], bf, a3[n3h], 0, 0, 0);
            }
        }
        #pragma unroll
        for (int n3h = 0; n3h < 4; ++n3h) {
            float bias = bu1[(half * 4 + n3h) * 16 + arow];
            #pragma unroll
            for (int rr = 0; rr < 4; ++rr) {
                float vv = gelu(a3[n3h][rr] + bias);
                int row = kgrp * 4 + rr;
                int byte = row * 128 + (((n3h * 16 + arow) * 2) ^ ((row & 7) << 4));
                myb[byte >> 1] = f2bf(vv);
            }
        }
        #pragma unroll
        for (int k4 = 0; k4 < 2; ++k4) {
            bf16x8 afu = *(const bf16x8*)(myb + ((arow * 128 + ((k4 * 64 + kgrp * 16) ^ ((arow & 7) << 4))) >> 1));
            #pragma unroll
            for (int n4 = 0; n4 < 8; ++n4) {
                bf16x8 bf = *(const bf16x8*)(sW4 + (size_t)(((n4 << 2) | (half * 2 + k4)) * 64 + lane) * 8);
                acc4[n4] = __builtin_amdgcn_mfma_f32_16x16x32_bf16(afu, bf, acc4[n4], 0, 0, 0);
            }
        }
    }
}

// ---- fused kernel: 768 threads = 12 waves/CU (3/SIMD) — clean occupancy test.
// LDS: W1 64K + W2 32K + W4 32K + 12x2K wave buffers = 152KB; W3 from L2.
__global__ __launch_bounds__(768, 3) void fused_kernel(
    const float* __restrict__ x, const float* __restrict__ bd,
    const float* __restrict__ lndg, const float* __restrict__ lndb,
    const short* __restrict__ pW1, const short* __restrict__ pW2,
    const short* __restrict__ pW3, const short* __restrict__ pW4,
    const float* __restrict__ bd1, const float* __restrict__ bd2,
    const float* __restrict__ lnug, const float* __restrict__ lnub,
    const float* __restrict__ bu1, const float* __restrict__ bu2,
    const int2* __restrict__ list1, const int* __restrict__ cnts1,
    const int* __restrict__ list2, const int* __restrict__ cnts2,
    const int* __restrict__ pernode, const ushort_t* __restrict__ bucket,
    float* __restrict__ out) {
    __shared__ short sW1[4096 * 8];
    __shared__ short sW2[2048 * 8];
    __shared__ short sW4[2048 * 8];
    __shared__ short sBuf[12][1024];   // 2KB per wave

    const int tid = threadIdx.x;
    for (int s = tid; s < 4096; s += 768)
        *(bf16x8*)(sW1 + s * 8) = *(const bf16x8*)(pW1 + (size_t)s * 8);
    for (int s = tid; s < 2048; s += 768)
        *(bf16x8*)(sW2 + s * 8) = *(const bf16x8*)(pW2 + (size_t)s * 8);
    for (int s = tid; s < 2048; s += 768)
        *(bf16x8*)(sW4 + s * 8) = *(const bf16x8*)(pW4 + (size_t)s * 8);
    __syncthreads();

    const int wave = tid >> 6, lane = tid & 63;
    short* myb = sBuf[wave];
    float* mf = (float*)myb;
    const int arow = lane & 15;
    const int kgrp = lane >> 4;
    const int q32 = lane >> 5, c32 = lane & 31;

    for (int w = blockIdx.x; w < T1MAX + T2MAX; w += gridDim.x) {
        const bool segA = w < T1MAX;
        int g, row0, nrow;
        if (segA) {
            g = w & 7; row0 = (w >> 3) * RPB + wave * 16; nrow = cnts1[g];
        } else {
            int w2 = w - T1MAX;
            g = w2 & 7; row0 = (w2 >> 3) * RPB + wave * 16; nrow = cnts2[g];
        }
        if (row0 >= nrow) continue;
        const float* x_g = x + (size_t)g * NS * DD;
        float* out_g = out + (size_t)g * NS * DD;
        const int gi = row0 + arow;
        const int gidx = gi < nrow ? gi : nrow - 1;

        int node, c = 1, pos0;
        int4 p8 = (int4){0, 0, 0, 0};
        if (segA) {
            int2 pn = list1[(size_t)g * NS + gidx];
            pos0 = pn.x; node = pn.y;
        } else {
            node = list2[(size_t)g * L2CAP + gidx];
            c = pernode[node * 8 + g];
            p8 = *(const int4*)(bucket + ((size_t)node * 8 + g) * 16);
            pos0 = p8.x & 0xffff;
        }

        // ---- gather: bd + x[pos0] (common), extra contributors (segB only)
        float v[32];
        {
            const float* xp = x_g + (size_t)pos0 * DD + kgrp * 8;
            const float* bp = bd + (size_t)node * DD + kgrp * 8;
            #pragma unroll
            for (int ks = 0; ks < 4; ++ks) {
                float4 a0 = *(const float4*)(xp + ks * 32);
                float4 a1 = *(const float4*)(xp + ks * 32 + 4);
                float4 b0 = *(const float4*)(bp + ks * 32);
                float4 b1 = *(const float4*)(bp + ks * 32 + 4);
                v[ks*8+0] = a0.x + b0.x; v[ks*8+1] = a0.y + b0.y;
                v[ks*8+2] = a0.z + b0.z; v[ks*8+3] = a0.w + b0.w;
                v[ks*8+4] = a1.x + b1.x; v[ks*8+5] = a1.y + b1.y;
                v[ks*8+6] = a1.z + b1.z; v[ks*8+7] = a1.w + b1.w;
            }
        }
        if (!segA) {
            const int pr1 = ((unsigned)p8.x) >> 16;     // c>=2 always in segB
            {
                const float* xq1 = x_g + (size_t)pr1 * DD + kgrp * 8;
                #pragma unroll
                for (int ks = 0; ks < 4; ++ks) {
                    float4 d0 = *(const float4*)(xq1 + ks * 32);
                    float4 d1 = *(const float4*)(xq1 + ks * 32 + 4);
                    v[ks*8+0] += d0.x; v[ks*8+1] += d0.y;
                    v[ks*8+2] += d0.z; v[ks*8+3] += d0.w;
                    v[ks*8+4] += d1.x; v[ks*8+5] += d1.y;
                    v[ks*8+6] += d1.z; v[ks*8+7] += d1.w;
                }
            }
            if (__any(c > 2)) {
                const int pr2 = p8.y & 0xffff, pr3 = ((unsigned)p8.y) >> 16;
                const float* xq2 = x_g + (size_t)((c > 2) ? pr2 : pos0) * DD + kgrp * 8;
                const float* xq3 = x_g + (size_t)((c > 3) ? pr3 : pos0) * DD + kgrp * 8;
                const float m2 = (c > 2) ? 1.f : 0.f;
                const float m3 = (c > 3) ? 1.f : 0.f;
                #pragma unroll
                for (int ks = 0; ks < 4; ++ks) {
                    float4 a0 = *(const float4*)(xq2 + ks * 32);
                    float4 a1 = *(const float4*)(xq2 + ks * 32 + 4);
                    float4 d0 = *(const float4*)(xq3 + ks * 32);
                    float4 d1 = *(const float4*)(xq3 + ks * 32 + 4);
                    v[ks*8+0] = fmaf(m3, d0.x, fmaf(m2, a0.x, v[ks*8+0]));
                    v[ks*8+1] = fmaf(m3, d0.y, fmaf(m2, a0.y, v[ks*8+1]));
                    v[ks*8+2] = fmaf(m3, d0.z, fmaf(m2, a0.z, v[ks*8+2]));
                    v[ks*8+3] = fmaf(m3, d0.w, fmaf(m2, a0.w, v[ks*8+3]));
                    v[ks*8+4] = fmaf(m3, d1.x, fmaf(m2, a1.x, v[ks*8+4]));
                    v[ks*8+5] = fmaf(m3, d1.y, fmaf(m2, a1.y, v[ks*8+5]));
                    v[ks*8+6] = fmaf(m3, d1.z, fmaf(m2, a1.z, v[ks*8+6]));
                    v[ks*8+7] = fmaf(m3, d1.w, fmaf(m2, a1.w, v[ks*8+7]));
                }
            }
            if (__any(c > 4)) {
                const ushort_t* bt = bucket + ((size_t)node * 8 + g) * 16;
                for (int j = 4; j < 16; j += 2) {
                    if (!__any(c > j)) break;
                    const int pa = (j < c) ? bt[j] : pos0;
                    const int pb = (j + 1 < c) ? bt[j + 1] : pos0;
                    const float ma = (j < c) ? 1.f : 0.f;
                    const float mb = (j + 1 < c) ? 1.f : 0.f;
                    const float* xqa = x_g + (size_t)pa * DD + kgrp * 8;
                    const float* xqb = x_g + (size_t)pb * DD + kgrp * 8;
                    #pragma unroll
                    for (int ks = 0; ks < 4; ++ks) {
                        float4 a0 = *(const float4*)(xqa + ks * 32);
                        float4 a1 = *(const float4*)(xqa + ks * 32 + 4);
                        float4 d0 = *(const float4*)(xqb + ks * 32);
                        float4 d1 = *(const float4*)(xqb + ks * 32 + 4);
                        v[ks*8+0] = fmaf(mb, d0.x, fmaf(ma, a0.x, v[ks*8+0]));
                        v[ks*8+1] = fmaf(mb, d0.y, fmaf(ma, a0.y, v[ks*8+1]));
                        v[ks*8+2] = fmaf(mb, d0.z, fmaf(ma, a0.z, v[ks*8+2]));
                        v[ks*8+3] = fmaf(mb, d0.w, fmaf(ma, a0.w, v[ks*8+3]));
                        v[ks*8+4] = fmaf(mb, d1.x, fmaf(ma, a1.x, v[ks*8+4]));
                        v[ks*8+5] = fmaf(mb, d1.y, fmaf(ma, a1.y, v[ks*8+5]));
                        v[ks*8+6] = fmaf(mb, d1.z, fmaf(ma, a1.z, v[ks*8+6]));
                        v[ks*8+7] = fmaf(mb, d1.w, fmaf(ma, a1.w, v[ks*8+7]));
                    }
                }
            }
        }

        bf16x8 afr[4];
        ln_d_pack(v, kgrp, lndg, lndb, afr);
        f32x4 acc4[8];
        mlp_core(afr, myb, arow, kgrp, sW1, sW2, pW3, sW4,
                 bd1, bd2, lnug, lnub, bu1, acc4);

        // ---- epilogue: stage rows in LDS -> 512B-contiguous stores (shared)
        #pragma unroll
        for (int rr = 0; rr < 4; ++rr) {
            #pragma unroll
            for (int n4 = 0; n4 < 8; ++n4) {
                int col = n4 * 16 + arow;
                int blk = (col >> 2) ^ kgrp;
                mf[kgrp * 128 + blk * 4 + (col & 3)] = acc4[n4][rr] + bu2[col];
            }
            #pragma unroll
            for (int pair = 0; pair < 2; ++pair) {
                int slot = pair * 2 + q32;
                int src = slot * 4 + rr;
                bool valid = (row0 + src) < nrow;
                float4 val = *(const float4*)(mf + slot * 128 + ((c32 ^ slot) * 4));
                if (segA) {
                    int p0v = __shfl(pos0, src);
                    if (valid)
                        *(float4*)(out_g + (size_t)p0v * DD + c32 * 4) = val;
                } else {
                    int c2 = __shfl(c, src);
                    if (!valid) c2 = 0;
                    unsigned u0 = (unsigned)__shfl(p8.x, src);
                    unsigned u1 = (unsigned)__shfl(p8.y, src);
                    unsigned u2 = (unsigned)__shfl(p8.z, src);
                    unsigned u3 = (unsigned)__shfl(p8.w, src);
                    if (c2 > 0) *(float4*)(out_g + (size_t)(u0 & 0xffff) * DD + c32 * 4) = val;
                    if (c2 > 1) *(float4*)(out_g + (size_t)(u0 >> 16) * DD + c32 * 4) = val;
                    if (c2 > 2) *(float4*)(out_g + (size_t)(u1 & 0xffff) * DD + c32 * 4) = val;
                    if (c2 > 3) *(float4*)(out_g + (size_t)(u1 >> 16) * DD + c32 * 4) = val;
                    if (__any(c2 > 4)) {
                        if (c2 > 4) *(float4*)(out_g + (size_t)(u2 & 0xffff) * DD + c32 * 4) = val;
                        if (c2 > 5) *(float4*)(out_g + (size_t)(u2 >> 16) * DD + c32 * 4) = val;
                        if (c2 > 6) *(float4*)(out_g + (size_t)(u3 & 0xffff) * DD + c32 * 4) = val;
                        if (c2 > 7) *(float4*)(out_g + (size_t)(u3 >> 16) * DD + c32 * 4) = val;
                    }
                    if (__any(c2 > 8)) {
                        int nd2 = __shfl(node, src);
                        const ushort_t* bt = bucket + ((size_t)nd2 * 8 + g) * 16;
                        for (int j = 8; j < 16; ++j) {
                            if (!__any(j < c2)) break;
                            if (j < c2)
                                *(float4*)(out_g + (size_t)bt[j] * DD + c32 * 4) = val;
                        }
                    }
                }
            }
        }
    }
}

extern "C" void kernel_launch(void* const* d_in, const int* in_sizes, int n_in,
                              void* d_out, int out_size, void* d_ws, size_t ws_size,
                              hipStream_t stream) {
    const float* x       = (const float*)d_in[0];
    const int*   indices = (const int*)d_in[1];
    const float* bd      = (const float*)d_in[2];
    const float* ln_d_g  = (const float*)d_in[3];
    const float* ln_d_b  = (const float*)d_in[4];
    const float* Wd1     = (const float*)d_in[5];
    const float* bd1     = (const float*)d_in[6];
    const float* Wd2     = (const float*)d_in[7];
    const float* bd2     = (const float*)d_in[8];
    const float* ln_u_g  = (const float*)d_in[9];
    const float* ln_u_b  = (const float*)d_in[10];
    const float* Wu1     = (const float*)d_in[11];
    const float* bu1     = (const float*)d_in[12];
    const float* Wu2     = (const float*)d_in[13];
    const float* bu2     = (const float*)d_in[14];
    float* out = (float*)d_out;

    char* ws = (char*)d_ws;
    size_t o = 0;
    auto alloc_b = [&](size_t bytes) { char* p = ws + o; o = (o + bytes + 255) & ~(size_t)255; return p; };
    // pernode + cnts1 + cnts2 contiguous -> zeroed by prep_all
    int*      pernode = (int*)alloc_b((size_t)NN * 8 * 4);
    int*      cnts1   = (int*)alloc_b(8 * 4);
    int*      cnts2   = (int*)alloc_b(8 * 4);
    int2*     list1   = (int2*)alloc_b((size_t)8 * NS * 8);
    int*      list2   = (int*)alloc_b((size_t)8 * L2CAP * 4);
    ushort_t* bucket  = (ushort_t*)alloc_b((size_t)NN * 8 * 16 * 2);
    short*    pW1     = (short*)alloc_b((size_t)4096 * 16);
    short*    pW2     = (short*)alloc_b((size_t)2048 * 16);
    short*    pW3     = (short*)alloc_b((size_t)1024 * 16);
    short*    pW4     = (short*)alloc_b((size_t)2048 * 16);

    prep_all<<<36 + (ZINT4 + 255) / 256, 256, 0, stream>>>(Wd1, Wd2, Wu1, Wu2,
                                                           pW1, pW2, pW3, pW4,
                                                           (int4*)pernode);
    flagfill_kernel<<<(G8 * NS + 255) / 256, 256, 0, stream>>>(indices, pernode, bucket);
    compact2_kernel<<<dim3((NN + 255) / 256, G8), 256, 0, stream>>>(indices, pernode,
                                                                    list1, cnts1,
                                                                    list2, cnts2);
    fused_kernel<<<256, 768, 0, stream>>>(x, bd, ln_d_g, ln_d_b,
                                          pW1, pW2, pW3, pW4,
                                          bd1, bd2, ln_u_g, ln_u_b, bu1, bu2,
                                          list1, cnts1, list2, cnts2,
                                          pernode, bucket, out);
}

// Round 18
// 403.157 us; speedup vs baseline: 1.1867x; 1.1867x over previous
//
#include <hip/hip_runtime.h>
#include <math.h>

#define NN 100000
#define DD 128
#define CC 64
#define TT 8
#define NS 50000
#define G8 8
#define MAXS 391            // A strips/g: ceil(50000/128)
#define MAXS_B 196          // B strips/g: ceil(25000/128)
#define T1MAX (G8 * MAXS)   // 3128
#define T2MAX (G8 * MAXS_B) // 1568
#define L2CAP 25000
#define ZINT4 200032        // (NN*8 + 128) ints / 4

typedef __attribute__((ext_vector_type(4))) float f32x4;
typedef __attribute__((ext_vector_type(8))) short bf16x8;
typedef unsigned short ushort_t;

__device__ __forceinline__ short f2bf(float f) {
    union { float f; unsigned u; } v; v.f = f;
    unsigned r = v.u + 0x7fffu + ((v.u >> 16) & 1u);
    return (short)(r >> 16);
}
__device__ __forceinline__ unsigned pk_bf16(float lo, float hi) {
    unsigned r;
    asm("v_cvt_pk_bf16_f32 %0, %1, %2" : "=v"(r) : "v"(lo), "v"(hi));
    return r;
}
// tanh-form GELU via hardware exp: max |diff| vs exact erf-GELU ~3e-3
__device__ __forceinline__ float gelu(float x) {
    float t = x + 0.044715f * x * x * x;
    return x / (1.0f + __expf(-1.5957691216f * t));
}

// ------- weights -> MFMA-fragment tables + zero pernode/cnts (one kernel) ----
__global__ void prep_all(const float* __restrict__ Wd1, const float* __restrict__ Wd2,
                         const float* __restrict__ Wu1, const float* __restrict__ Wu2,
                         short* __restrict__ pW1, short* __restrict__ pW2,
                         short* __restrict__ pW3, short* __restrict__ pW4,
                         int4* __restrict__ zbase) {
    int b = blockIdx.x;
    if (b >= 36) {
        int i = (b - 36) * 256 + threadIdx.x;
        if (i < ZINT4) zbase[i] = (int4){0, 0, 0, 0};
        return;
    }
    const float* W; short* dst; int KSTEPS, total, N, s0;
    if (b < 16)      { W = Wd1; dst = pW1; KSTEPS = 4; total = 4096; N = 256; s0 = b * 256; }
    else if (b < 24) { W = Wd2; dst = pW2; KSTEPS = 8; total = 2048; N = 64;  s0 = (b - 16) * 256; }
    else if (b < 28) { W = Wu1; dst = pW3; KSTEPS = 2; total = 1024; N = 128; s0 = (b - 24) * 256; }
    else             { W = Wu2; dst = pW4; KSTEPS = 4; total = 2048; N = 128; s0 = (b - 28) * 256; }
    int s = s0 + threadIdx.x;
    if (s >= total) return;
    int lane = s & 63;
    int ks = (s >> 6) % KSTEPS;
    int n = s / (64 * KSTEPS);
    int kb = ks * 32 + (lane >> 4) * 8;
    int col = n * 16 + (lane & 15);
    bf16x8 o;
    #pragma unroll
    for (int j = 0; j < 8; ++j) o[j] = f2bf(W[(size_t)(kb + j) * N + col]);
    *(bf16x8*)(dst + (size_t)s * 8) = o;
}

// -------- count + record contributor positions (packed u16 buckets) --------
__global__ void flagfill_kernel(const int* __restrict__ idx, int* __restrict__ pernode,
                                ushort_t* __restrict__ bucket) {
    int i = blockIdx.x * 256 + threadIdx.x;
    if (i >= G8 * NS) return;
    int g = i / NS, s = i - g * NS;
    int node = idx[i];
    int p = atomicAdd(&pernode[node * 8 + g], 1);
    if (p < 16) bucket[((size_t)node * 8 + g) * 16 + p] = (ushort_t)s;
}

// ------ list1: {pos,node} pairs with c==1; list2: nodes with c>=2 ----------
__global__ void compact2_kernel(const int* __restrict__ idx, const int* __restrict__ pernode,
                                int2* __restrict__ list1, int* __restrict__ cnts1,
                                int* __restrict__ list2, int* __restrict__ cnts2) {
    int g = blockIdx.y;
    int i = blockIdx.x * 256 + threadIdx.x;
    int lane = threadIdx.x & 63;
    bool a1 = false;
    int nd1 = 0;
    if (i < NS) {
        nd1 = idx[(size_t)g * NS + i];
        a1 = (pernode[nd1 * 8 + g] == 1);
    }
    unsigned long long m1 = __ballot(a1);
    int r1 = __popcll(m1 & ((1ull << lane) - 1ull));
    int c1 = __popcll(m1);
    int b1 = 0;
    if (lane == 0 && c1 > 0) b1 = atomicAdd(&cnts1[g], c1);
    b1 = __shfl(b1, 0);
    if (a1) list1[(size_t)g * NS + b1 + r1] = (int2){i, nd1};
    bool a2 = (i < NN) && (pernode[i * 8 + g] >= 2);
    unsigned long long m2 = __ballot(a2);
    int r2 = __popcll(m2 & ((1ull << lane) - 1ull));
    int c2 = __popcll(m2);
    int b2 = 0;
    if (lane == 0 && c2 > 0) b2 = atomicAdd(&cnts2[g], c2);
    b2 = __shfl(b2, 0);
    if (a2) list2[(size_t)g * L2CAP + b2 + r2] = i;
}

// ---- LN_d in A-fragment layout: v[32] -> afr[4]
__device__ __forceinline__ void ln_d_pack(
    const float (&v)[32], int kgrp,
    const float* __restrict__ lndg, const float* __restrict__ lndb, bf16x8 (&afr)[4]) {
    float s1 = 0.f;
    #pragma unroll
    for (int j = 0; j < 32; ++j) s1 += v[j];
    s1 += __shfl_xor(s1, 16); s1 += __shfl_xor(s1, 32);
    float mu = s1 * 0.0078125f;
    float s2 = 0.f;
    #pragma unroll
    for (int j = 0; j < 32; ++j) { float d = v[j] - mu; s2 += d * d; }
    s2 += __shfl_xor(s2, 16); s2 += __shfl_xor(s2, 32);
    float rs = rsqrtf(s2 * 0.0078125f + 1e-5f);
    union U8 { bf16x8 v8; unsigned u[4]; };
    const float* gp = lndg + kgrp * 8;
    const float* bbp = lndb + kgrp * 8;
    #pragma unroll
    for (int ks = 0; ks < 4; ++ks) {
        float4 g0 = *(const float4*)(gp + ks * 32);
        float4 g1 = *(const float4*)(gp + ks * 32 + 4);
        float4 c0 = *(const float4*)(bbp + ks * 32);
        float4 c1 = *(const float4*)(bbp + ks * 32 + 4);
        U8 t;
        t.u[0] = pk_bf16((v[ks*8+0]-mu)*rs*g0.x + c0.x, (v[ks*8+1]-mu)*rs*g0.y + c0.y);
        t.u[1] = pk_bf16((v[ks*8+2]-mu)*rs*g0.z + c0.z, (v[ks*8+3]-mu)*rs*g0.w + c0.w);
        t.u[2] = pk_bf16((v[ks*8+4]-mu)*rs*g1.x + c1.x, (v[ks*8+5]-mu)*rs*g1.y + c1.y);
        t.u[3] = pk_bf16((v[ks*8+6]-mu)*rs*g1.z + c1.z, (v[ks*8+7]-mu)*rs*g1.w + c1.w);
        afr[ks] = t.v8;
    }
}

// ---- MLP core: 64-col ping-pong chunks (4 turnarounds) + single-shot G3/G4.
// W1, W2, W4 from LDS (proven mandatory); W3 (16KB) from global/L2 (proven OK).
__device__ __forceinline__ void mlp_core(
    const bf16x8 (&afr)[4], short* myb, int arow, int kgrp,
    const short* sW1, const short* sW2, const short* __restrict__ pW3, const short* sW4,
    const float* __restrict__ bd1, const float* __restrict__ bd2,
    const float* __restrict__ lnug, const float* __restrict__ lnub,
    const float* __restrict__ bu1, f32x4 (&acc4)[8]) {
    const int lane = kgrp * 16 + arow;
    f32x4 acc2[4];
    #pragma unroll
    for (int n = 0; n < 4; ++n) acc2[n] = (f32x4){0.f, 0.f, 0.f, 0.f};
    // ---- GEMM1+GELU+GEMM2 in 4 chunks of 64 H-cols, ping-pong 2KB halves:
    // chunk ch+1's G1 MFMAs overlap chunk ch's LDS write->read turnaround.
    #pragma unroll
    for (int ch = 0; ch < 4; ++ch) {
        short* hb = myb + (ch & 1) * 1024;
        f32x4 a1v[4];
        #pragma unroll
        for (int p = 0; p < 4; ++p) a1v[p] = (f32x4){0.f, 0.f, 0.f, 0.f};
        #pragma unroll
        for (int ks1 = 0; ks1 < 4; ++ks1) {
            #pragma unroll
            for (int p = 0; p < 4; ++p) {
                int n1 = ch * 4 + p;
                bf16x8 bf = *(const bf16x8*)(sW1 + (size_t)(((n1 << 2) | ks1) * 64 + lane) * 8);
                a1v[p] = __builtin_amdgcn_mfma_f32_16x16x32_bf16(afr[ks1], bf, a1v[p], 0, 0, 0);
            }
        }
        #pragma unroll
        for (int p = 0; p < 4; ++p) {
            float bias = bd1[(ch * 4 + p) * 16 + arow];
            #pragma unroll
            for (int rr = 0; rr < 4; ++rr) {
                int row = kgrp * 4 + rr;
                int byte = row * 128 + (((p * 16 + arow) * 2) ^ ((row & 7) << 4));
                hb[byte >> 1] = f2bf(gelu(a1v[p][rr] + bias));
            }
        }
        #pragma unroll
        for (int ksc = 0; ksc < 2; ++ksc) {
            int byte = arow * 128 + ((ksc * 64 + kgrp * 16) ^ ((arow & 7) << 4));
            bf16x8 af2 = *(const bf16x8*)(hb + (byte >> 1));
            int ks2 = ch * 2 + ksc;
            #pragma unroll
            for (int n2 = 0; n2 < 4; ++n2) {
                bf16x8 bf = *(const bf16x8*)(sW2 + (size_t)(((n2 << 3) | ks2) * 64 + lane) * 8);
                acc2[n2] = __builtin_amdgcn_mfma_f32_16x16x32_bf16(af2, bf, acc2[n2], 0, 0, 0);
            }
        }
    }
    // ---- + bd2, LN_u over C=64 -> U [16][64] bf16 at half 0 (1 turnaround)
    float hv[4][4];
    #pragma unroll
    for (int n2 = 0; n2 < 4; ++n2)
        #pragma unroll
        for (int rr = 0; rr < 4; ++rr)
            hv[n2][rr] = acc2[n2][rr] + bd2[n2 * 16 + arow];
    #pragma unroll
    for (int rr = 0; rr < 4; ++rr) {
        float sr = hv[0][rr] + hv[1][rr] + hv[2][rr] + hv[3][rr];
        sr += __shfl_xor(sr, 1); sr += __shfl_xor(sr, 2);
        sr += __shfl_xor(sr, 4); sr += __shfl_xor(sr, 8);
        float mu_u = sr * 0.015625f;
        float sq = 0.f;
        #pragma unroll
        for (int n2 = 0; n2 < 4; ++n2) { float d = hv[n2][rr] - mu_u; sq += d * d; }
        sq += __shfl_xor(sq, 1); sq += __shfl_xor(sq, 2);
        sq += __shfl_xor(sq, 4); sq += __shfl_xor(sq, 8);
        float rs_u = rsqrtf(sq * 0.015625f + 1e-5f);
        #pragma unroll
        for (int n2 = 0; n2 < 4; ++n2) {
            int cidx = n2 * 16 + arow;
            float nv = (hv[n2][rr] - mu_u) * rs_u * lnug[cidx] + lnub[cidx];
            int row = kgrp * 4 + rr;
            int byte = row * 128 + ((cidx * 2) ^ ((row & 7) << 4));
            myb[byte >> 1] = f2bf(nv);
        }
    }
    bf16x8 af3[2];
    #pragma unroll
    for (int ks3 = 0; ks3 < 2; ++ks3) {
        int byte = arow * 128 + ((ks3 * 64 + kgrp * 16) ^ ((arow & 7) << 4));
        af3[ks3] = *(const bf16x8*)(myb + (byte >> 1));
    }
    // ---- GEMM3 full (K=64 -> 128, W3 frags from L2); single G3out turnaround
    f32x4 a3[8];
    #pragma unroll
    for (int n = 0; n < 8; ++n) a3[n] = (f32x4){0.f, 0.f, 0.f, 0.f};
    #pragma unroll
    for (int ks3 = 0; ks3 < 2; ++ks3) {
        #pragma unroll
        for (int n3 = 0; n3 < 8; ++n3) {
            bf16x8 bf = *(const bf16x8*)(pW3 + (size_t)(((n3 << 1) | ks3) * 64 + lane) * 8);
            a3[n3] = __builtin_amdgcn_mfma_f32_16x16x32_bf16(af3[ks3], bf, a3[n3], 0, 0, 0);
        }
    }
    // G3out [16][128] bf16 across the full 4KB buffer (256B rows, swz (row&15)<<4)
    #pragma unroll
    for (int n3 = 0; n3 < 8; ++n3) {
        float bias = bu1[n3 * 16 + arow];
        #pragma unroll
        for (int rr = 0; rr < 4; ++rr) {
            int row = kgrp * 4 + rr;
            int byte = row * 256 + (((n3 * 16 + arow) * 2) ^ ((row & 15) << 4));
            myb[byte >> 1] = f2bf(gelu(a3[n3][rr] + bias));
        }
    }
    #pragma unroll
    for (int n = 0; n < 8; ++n) acc4[n] = (f32x4){0.f, 0.f, 0.f, 0.f};
    #pragma unroll
    for (int k4 = 0; k4 < 4; ++k4) {
        int byte = arow * 256 + ((k4 * 64 + kgrp * 16) ^ ((arow & 15) << 4));
        bf16x8 afu = *(const bf16x8*)(myb + (byte >> 1));
        #pragma unroll
        for (int n4 = 0; n4 < 8; ++n4) {
            bf16x8 bf = *(const bf16x8*)(sW4 + (size_t)(((n4 << 2) | k4) * 64 + lane) * 8);
            acc4[n4] = __builtin_amdgcn_mfma_f32_16x16x32_bf16(afu, bf, acc4[n4], 0, 0, 0);
        }
    }
}

// ---- fused kernel, unified single path. 512 threads = 8 waves.
// LDS: W1 64K + W2 32K + W4 32K + 8x4K wave buffers = 160KB exactly; W3 from L2.
__global__ __launch_bounds__(512, 2) void fused_kernel(
    const float* __restrict__ x, const float* __restrict__ bd,
    const float* __restrict__ lndg, const float* __restrict__ lndb,
    const short* __restrict__ pW1, const short* __restrict__ pW2,
    const short* __restrict__ pW3, const short* __restrict__ pW4,
    const float* __restrict__ bd1, const float* __restrict__ bd2,
    const float* __restrict__ lnug, const float* __restrict__ lnub,
    const float* __restrict__ bu1, const float* __restrict__ bu2,
    const int2* __restrict__ list1, const int* __restrict__ cnts1,
    const int* __restrict__ list2, const int* __restrict__ cnts2,
    const int* __restrict__ pernode, const ushort_t* __restrict__ bucket,
    float* __restrict__ out) {
    __shared__ short sW1[4096 * 8];
    __shared__ short sW2[2048 * 8];
    __shared__ short sW4[2048 * 8];
    __shared__ short sBuf[8][2048];   // 4KB per wave

    const int tid = threadIdx.x;
    for (int s = tid; s < 4096; s += 512)
        *(bf16x8*)(sW1 + s * 8) = *(const bf16x8*)(pW1 + (size_t)s * 8);
    for (int s = tid; s < 2048; s += 512)
        *(bf16x8*)(sW2 + s * 8) = *(const bf16x8*)(pW2 + (size_t)s * 8);
    for (int s = tid; s < 2048; s += 512)
        *(bf16x8*)(sW4 + s * 8) = *(const bf16x8*)(pW4 + (size_t)s * 8);
    __syncthreads();

    const int wave = tid >> 6, lane = tid & 63;
    short* myb = sBuf[wave];
    float* mf = (float*)myb;
    const int arow = lane & 15;
    const int kgrp = lane >> 4;
    const int q32 = lane >> 5, c32 = lane & 31;

    for (int w = blockIdx.x; w < T1MAX + T2MAX; w += gridDim.x) {
        const bool segA = w < T1MAX;
        int g, row0, nrow;
        if (segA) {
            g = w & 7; row0 = (w >> 3) * 128 + wave * 16; nrow = cnts1[g];
        } else {
            int w2 = w - T1MAX;
            g = w2 & 7; row0 = (w2 >> 3) * 128 + wave * 16; nrow = cnts2[g];
        }
        if (row0 >= nrow) continue;
        const float* x_g = x + (size_t)g * NS * DD;
        float* out_g = out + (size_t)g * NS * DD;
        const int gi = row0 + arow;
        const int gidx = gi < nrow ? gi : nrow - 1;

        int node, c = 1, pos0;
        int4 p8 = (int4){0, 0, 0, 0};
        if (segA) {
            int2 pn = list1[(size_t)g * NS + gidx];
            pos0 = pn.x; node = pn.y;
        } else {
            node = list2[(size_t)g * L2CAP + gidx];
            c = pernode[node * 8 + g];
            p8 = *(const int4*)(bucket + ((size_t)node * 8 + g) * 16);
            pos0 = p8.x & 0xffff;
        }

        // ---- gather: bd + x[pos0] (common), extra contributors (segB only)
        float v[32];
        {
            const float* xp = x_g + (size_t)pos0 * DD + kgrp * 8;
            const float* bp = bd + (size_t)node * DD + kgrp * 8;
            #pragma unroll
            for (int ks = 0; ks < 4; ++ks) {
                float4 a0 = *(const float4*)(xp + ks * 32);
                float4 a1 = *(const float4*)(xp + ks * 32 + 4);
                float4 b0 = *(const float4*)(bp + ks * 32);
                float4 b1 = *(const float4*)(bp + ks * 32 + 4);
                v[ks*8+0] = a0.x + b0.x; v[ks*8+1] = a0.y + b0.y;
                v[ks*8+2] = a0.z + b0.z; v[ks*8+3] = a0.w + b0.w;
                v[ks*8+4] = a1.x + b1.x; v[ks*8+5] = a1.y + b1.y;
                v[ks*8+6] = a1.z + b1.z; v[ks*8+7] = a1.w + b1.w;
            }
        }
        if (!segA) {
            const int pr1 = ((unsigned)p8.x) >> 16;     // c>=2 always in segB
            {
                const float* xq1 = x_g + (size_t)pr1 * DD + kgrp * 8;
                #pragma unroll
                for (int ks = 0; ks < 4; ++ks) {
                    float4 d0 = *(const float4*)(xq1 + ks * 32);
                    float4 d1 = *(const float4*)(xq1 + ks * 32 + 4);
                    v[ks*8+0] += d0.x; v[ks*8+1] += d0.y;
                    v[ks*8+2] += d0.z; v[ks*8+3] += d0.w;
                    v[ks*8+4] += d1.x; v[ks*8+5] += d1.y;
                    v[ks*8+6] += d1.z; v[ks*8+7] += d1.w;
                }
            }
            if (__any(c > 2)) {
                const int pr2 = p8.y & 0xffff, pr3 = ((unsigned)p8.y) >> 16;
                const float* xq2 = x_g + (size_t)((c > 2) ? pr2 : pos0) * DD + kgrp * 8;
                const float* xq3 = x_g + (size_t)((c > 3) ? pr3 : pos0) * DD + kgrp * 8;
                const float m2 = (c > 2) ? 1.f : 0.f;
                const float m3 = (c > 3) ? 1.f : 0.f;
                #pragma unroll
                for (int ks = 0; ks < 4; ++ks) {
                    float4 a0 = *(const float4*)(xq2 + ks * 32);
                    float4 a1 = *(const float4*)(xq2 + ks * 32 + 4);
                    float4 d0 = *(const float4*)(xq3 + ks * 32);
                    float4 d1 = *(const float4*)(xq3 + ks * 32 + 4);
                    v[ks*8+0] = fmaf(m3, d0.x, fmaf(m2, a0.x, v[ks*8+0]));
                    v[ks*8+1] = fmaf(m3, d0.y, fmaf(m2, a0.y, v[ks*8+1]));
                    v[ks*8+2] = fmaf(m3, d0.z, fmaf(m2, a0.z, v[ks*8+2]));
                    v[ks*8+3] = fmaf(m3, d0.w, fmaf(m2, a0.w, v[ks*8+3]));
                    v[ks*8+4] = fmaf(m3, d1.x, fmaf(m2, a1.x, v[ks*8+4]));
                    v[ks*8+5] = fmaf(m3, d1.y, fmaf(m2, a1.y, v[ks*8+5]));
                    v[ks*8+6] = fmaf(m3, d1.z, fmaf(m2, a1.z, v[ks*8+6]));
                    v[ks*8+7] = fmaf(m3, d1.w, fmaf(m2, a1.w, v[ks*8+7]));
                }
            }
            if (__any(c > 4)) {
                const ushort_t* bt = bucket + ((size_t)node * 8 + g) * 16;
                for (int j = 4; j < 16; j += 2) {
                    if (!__any(c > j)) break;
                    const int pa = (j < c) ? bt[j] : pos0;
                    const int pb = (j + 1 < c) ? bt[j + 1] : pos0;
                    const float ma = (j < c) ? 1.f : 0.f;
                    const float mb = (j + 1 < c) ? 1.f : 0.f;
                    const float* xqa = x_g + (size_t)pa * DD + kgrp * 8;
                    const float* xqb = x_g + (size_t)pb * DD + kgrp * 8;
                    #pragma unroll
                    for (int ks = 0; ks < 4; ++ks) {
                        float4 a0 = *(const float4*)(xqa + ks * 32);
                        float4 a1 = *(const float4*)(xqa + ks * 32 + 4);
                        float4 d0 = *(const float4*)(xqb + ks * 32);
                        float4 d1 = *(const float4*)(xqb + ks * 32 + 4);
                        v[ks*8+0] = fmaf(mb, d0.x, fmaf(ma, a0.x, v[ks*8+0]));
                        v[ks*8+1] = fmaf(mb, d0.y, fmaf(ma, a0.y, v[ks*8+1]));
                        v[ks*8+2] = fmaf(mb, d0.z, fmaf(ma, a0.z, v[ks*8+2]));
                        v[ks*8+3] = fmaf(mb, d0.w, fmaf(ma, a0.w, v[ks*8+3]));
                        v[ks*8+4] = fmaf(mb, d1.x, fmaf(ma, a1.x, v[ks*8+4]));
                        v[ks*8+5] = fmaf(mb, d1.y, fmaf(ma, a1.y, v[ks*8+5]));
                        v[ks*8+6] = fmaf(mb, d1.z, fmaf(ma, a1.z, v[ks*8+6]));
                        v[ks*8+7] = fmaf(mb, d1.w, fmaf(ma, a1.w, v[ks*8+7]));
                    }
                }
            }
        }

        bf16x8 afr[4];
        ln_d_pack(v, kgrp, lndg, lndb, afr);
        f32x4 acc4[8];
        mlp_core(afr, myb, arow, kgrp, sW1, sW2, pW3, sW4,
                 bd1, bd2, lnug, lnub, bu1, acc4);

        // ---- epilogue: stage rows in LDS -> 512B-contiguous stores (shared)
        #pragma unroll
        for (int rr = 0; rr < 4; ++rr) {
            #pragma unroll
            for (int n4 = 0; n4 < 8; ++n4) {
                int col = n4 * 16 + arow;
                int blk = (col >> 2) ^ kgrp;
                mf[kgrp * 128 + blk * 4 + (col & 3)] = acc4[n4][rr] + bu2[col];
            }
            #pragma unroll
            for (int pair = 0; pair < 2; ++pair) {
                int slot = pair * 2 + q32;
                int src = slot * 4 + rr;
                bool valid = (row0 + src) < nrow;
                float4 val = *(const float4*)(mf + slot * 128 + ((c32 ^ slot) * 4));
                if (segA) {
                    int p0v = __shfl(pos0, src);
                    if (valid)
                        *(float4*)(out_g + (size_t)p0v * DD + c32 * 4) = val;
                } else {
                    int c2 = __shfl(c, src);
                    if (!valid) c2 = 0;
                    unsigned u0 = (unsigned)__shfl(p8.x, src);
                    unsigned u1 = (unsigned)__shfl(p8.y, src);
                    unsigned u2 = (unsigned)__shfl(p8.z, src);
                    unsigned u3 = (unsigned)__shfl(p8.w, src);
                    if (c2 > 0) *(float4*)(out_g + (size_t)(u0 & 0xffff) * DD + c32 * 4) = val;
                    if (c2 > 1) *(float4*)(out_g + (size_t)(u0 >> 16) * DD + c32 * 4) = val;
                    if (c2 > 2) *(float4*)(out_g + (size_t)(u1 & 0xffff) * DD + c32 * 4) = val;
                    if (c2 > 3) *(float4*)(out_g + (size_t)(u1 >> 16) * DD + c32 * 4) = val;
                    if (__any(c2 > 4)) {
                        if (c2 > 4) *(float4*)(out_g + (size_t)(u2 & 0xffff) * DD + c32 * 4) = val;
                        if (c2 > 5) *(float4*)(out_g + (size_t)(u2 >> 16) * DD + c32 * 4) = val;
                        if (c2 > 6) *(float4*)(out_g + (size_t)(u3 & 0xffff) * DD + c32 * 4) = val;
                        if (c2 > 7) *(float4*)(out_g + (size_t)(u3 >> 16) * DD + c32 * 4) = val;
                    }
                    if (__any(c2 > 8)) {
                        int nd2 = __shfl(node, src);
                        const ushort_t* bt = bucket + ((size_t)nd2 * 8 + g) * 16;
                        for (int j = 8; j < 16; ++j) {
                            if (!__any(j < c2)) break;
                            if (j < c2)
                                *(float4*)(out_g + (size_t)bt[j] * DD + c32 * 4) = val;
                        }
                    }
                }
            }
        }
    }
}

extern "C" void kernel_launch(void* const* d_in, const int* in_sizes, int n_in,
                              void* d_out, int out_size, void* d_ws, size_t ws_size,
                              hipStream_t stream) {
    const float* x       = (const float*)d_in[0];
    const int*   indices = (const int*)d_in[1];
    const float* bd      = (const float*)d_in[2];
    const float* ln_d_g  = (const float*)d_in[3];
    const float* ln_d_b  = (const float*)d_in[4];
    const float* Wd1     = (const float*)d_in[5];
    const float* bd1     = (const float*)d_in[6];
    const float* Wd2     = (const float*)d_in[7];
    const float* bd2     = (const float*)d_in[8];
    const float* ln_u_g  = (const float*)d_in[9];
    const float* ln_u_b  = (const float*)d_in[10];
    const float* Wu1     = (const float*)d_in[11];
    const float* bu1     = (const float*)d_in[12];
    const float* Wu2     = (const float*)d_in[13];
    const float* bu2     = (const float*)d_in[14];
    float* out = (float*)d_out;

    char* ws = (char*)d_ws;
    size_t o = 0;
    auto alloc_b = [&](size_t bytes) { char* p = ws + o; o = (o + bytes + 255) & ~(size_t)255; return p; };
    // pernode + cnts1 + cnts2 contiguous -> zeroed by prep_all
    int*      pernode = (int*)alloc_b((size_t)NN * 8 * 4);
    int*      cnts1   = (int*)alloc_b(8 * 4);
    int*      cnts2   = (int*)alloc_b(8 * 4);
    int2*     list1   = (int2*)alloc_b((size_t)8 * NS * 8);
    int*      list2   = (int*)alloc_b((size_t)8 * L2CAP * 4);
    ushort_t* bucket  = (ushort_t*)alloc_b((size_t)NN * 8 * 16 * 2);
    short*    pW1     = (short*)alloc_b((size_t)4096 * 16);
    short*    pW2     = (short*)alloc_b((size_t)2048 * 16);
    short*    pW3     = (short*)alloc_b((size_t)1024 * 16);
    short*    pW4     = (short*)alloc_b((size_t)2048 * 16);

    prep_all<<<36 + (ZINT4 + 255) / 256, 256, 0, stream>>>(Wd1, Wd2, Wu1, Wu2,
                                                           pW1, pW2, pW3, pW4,
                                                           (int4*)pernode);
    flagfill_kernel<<<(G8 * NS + 255) / 256, 256, 0, stream>>>(indices, pernode, bucket);
    compact2_kernel<<<dim3((NN + 255) / 256, G8), 256, 0, stream>>>(indices, pernode,
                                                                    list1, cnts1,
                                                                    list2, cnts2);
    fused_kernel<<<256, 512, 0, stream>>>(x, bd, ln_d_g, ln_d_b,
                                          pW1, pW2, pW3, pW4,
                                          bd1, bd2, ln_u_g, ln_u_b, bu1, bu2,
                                          list1, cnts1, list2, cnts2,
                                          pernode, bucket, out);
}